// Round 13
// baseline (126.416 us; speedup 1.0000x reference)
//
#include <hip/hip_runtime.h>
#include <stdint.h>

#define ND   4096               // row stride (floats) for x / upfold / out
#define NT   16                 // O tiles of 64
#define UBB  9216               // Ub: 64 rows x 72 halves
#define UTB  16896              // Ut3: 64 rows x 132 halves (padded, 2-way free)
#define BUFB (UBB + UTB)        // 26112 per buffer

typedef float    floatx16 __attribute__((ext_vector_type(16)));
typedef _Float16 half8    __attribute__((ext_vector_type(8)));
typedef _Float16 h2       __attribute__((ext_vector_type(2)));
typedef __fp16   fp16x2   __attribute__((ext_vector_type(2)));

__device__ __forceinline__ uint32_t pkh2(float a, float b) {
    fp16x2 p = __builtin_amdgcn_cvt_pkrtz(a, b);   // v_cvt_pkrtz_f16_f32
    return __builtin_bit_cast(uint32_t, p);
}

__device__ __forceinline__ half8 mk_frag(uint32_t a, uint32_t b, uint32_t c, uint32_t d) {
    union { uint32_t u[4]; half8 v; } U;
    U.u[0] = a; U.u[1] = b; U.u[2] = c; U.u[3] = d;
    return U.v;
}

// sigmoid(s/8) - 0.5 = 0.5*tanh(s/16), odd poly in v=(s/16)^2, packed fp16.
__device__ __forceinline__ uint32_t psig(float s0, float s1) {
    const h2 HI = {(_Float16)41.6f,        (_Float16)41.6f};
    const h2 LO = {(_Float16)-41.6f,       (_Float16)-41.6f};
    const h2 SC = {(_Float16)0.0625f,      (_Float16)0.0625f};
    const h2 C0 = {(_Float16)0.03099238f,  (_Float16)0.03099238f};
    const h2 C1 = {(_Float16)-0.00842090f, (_Float16)-0.00842090f};
    const h2 C2 = {(_Float16)0.00151845f,  (_Float16)0.00151845f};
    const h2 C3 = {(_Float16)-1.02197e-4f, (_Float16)-1.02197e-4f};
    h2 s = __builtin_bit_cast(h2, pkh2(s0, s1));
    s = __builtin_elementwise_min(s, HI);
    s = __builtin_elementwise_max(s, LO);
    h2 ha = s * SC;
    h2 v  = ha * ha;
    h2 w  = C2 + v * C3;
    w     = C1 + v * w;
    w     = C0 + v * w;
    h2 f  = s * w;
    return __builtin_bit_cast(uint32_t, f);
}

__global__ void __launch_bounds__(256, 2)
corr_kernel(const float* __restrict__ x, const float* __restrict__ up,
            float* __restrict__ out)
{
    __shared__ __align__(16) uint8_t smem[2 * BUFB];

    const int tid  = threadIdx.x;
    const int lane = tid & 63;
    const int wid  = tid >> 6;
    const int l31  = lane & 31;
    const int h    = lane >> 5;          // wave half
    const int r8   = tid >> 4;           // staging row-group (0..15)
    const int c    = tid & 15;           // staging col quad: d = 4c..4c+3
    const int n    = blockIdx.x;         // XCD swizzle: same n -> same XCD
    const int lb   = blockIdx.y;
    const int lw   = lb * 128 + wid * 32 + l31;

    const float* ubase = up + (size_t)n * 64;

    // coalesced 64-o tile load: rows 2r8+32j (va) / +1 (vb), cols 4c..4c+3
    float4 va[2], vb[2];
    auto load_tile = [&](int ot) {
        const float* pr = ubase + (size_t)(ot * 64 + 2 * r8) * ND + 4 * c;
        #pragma unroll
        for (int j = 0; j < 2; ++j) {
            va[j] = *(const float4*)(pr + (size_t)(32 * j) * ND);
            vb[j] = *(const float4*)(pr + (size_t)(32 * j) * ND + ND);
        }
    };
    // stage regs -> buf b: Ub[64][72] rows + Ut3[64][132] transposed (o-pair b32)
    auto stage_tile = [&](int b) {
        uint16_t (*Ub)[72]   = (uint16_t (*)[72])(smem + b * BUFB);
        uint16_t (*Ut3)[132] = (uint16_t (*)[132])(smem + b * BUFB + UBB);
        #pragma unroll
        for (int j = 0; j < 2; ++j) {
            const float av[4] = {va[j].x, va[j].y, va[j].z, va[j].w};
            const float bv[4] = {vb[j].x, vb[j].y, vb[j].z, vb[j].w};
            *(uint2*)&Ub[2*r8 + 32*j][4*c] =
                make_uint2(pkh2(av[0], av[1]), pkh2(av[2], av[3]));
            *(uint2*)&Ub[2*r8 + 32*j + 1][4*c] =
                make_uint2(pkh2(bv[0], bv[1]), pkh2(bv[2], bv[3]));
            #pragma unroll
            for (int k = 0; k < 4; ++k)
                *(uint32_t*)&Ut3[4*c + k][2 * (r8 + 16*j)] = pkh2(av[k], bv[k]);
        }
    };

    load_tile(0);   // longest-latency path first

    // ---- phase 0: X tile (128 rows) -> LDS fp32 overlay, build Xf frags ----
    half8 Xf[4];
    {
        float (*Xs)[68] = (float (*)[68])smem;     // 34816 B overlay
        const int xr = tid >> 1;
        const int xh = tid & 1;
        const float* xsrc = x + (size_t)(lb * 128 + xr) * ND + n * 64;
        #pragma unroll
        for (int j = 0; j < 8; ++j) {
            const int f4i = xh * 8 + j;
            *(float4*)&Xs[xr][4 * f4i] = *(const float4*)(xsrc + 4 * f4i);
        }
        __syncthreads();
        const int rl = wid * 32 + l31;
        #pragma unroll
        for (int kk = 0; kk < 4; ++kk) {
            float4 f1 = *(const float4*)&Xs[rl][16 * kk + 8 * h];
            float4 f2 = *(const float4*)&Xs[rl][16 * kk + 8 * h + 4];
            Xf[kk] = mk_frag(pkh2(f1.x, f1.y), pkh2(f1.z, f1.w),
                             pkh2(f2.x, f2.y), pkh2(f2.z, f2.w));
        }
        __syncthreads();   // Xs reads done before buf0 staging overwrites
    }

    stage_tile(0);
    load_tile(1);
    __syncthreads();

    floatx16 F0, F1;           // F^T accumulators, d 0..31 / 32..63
    #pragma unroll
    for (int i = 0; i < 16; ++i) { F0[i] = 0.0f; F1[i] = 0.0f; }

    floatx16 Sp0, Sp1;         // S of previous tile (carried)
    half8 A2p0[4], A2p1[4];    // GEMM2 A-frags of previous tile (carried)

    // ---- software-pipelined main loop: GEMM1(t) overlaps GEMM2(t-1) ----
    for (int t = 0; t <= NT; ++t) {
        const int b = t & 1;
        uint16_t (*Ub)[72]   = (uint16_t (*)[72])(smem + b * BUFB);
        uint16_t (*Ut3)[132] = (uint16_t (*)[132])(smem + b * BUFB + UBB);

        half8 A10[4], A11[4];
        if (t < NT) {
            #pragma unroll
            for (int kk = 0; kk < 4; ++kk) {
                A10[kk] = *(const half8*)&Ub[l31][16 * kk + 8 * h];
                A11[kk] = *(const half8*)&Ub[32 + l31][16 * kk + 8 * h];
            }
        }

        uint32_t P[16], R[8];
        if (t > 0) {           // weights of tile t-1 (early: feeds MFMA block)
            #pragma unroll
            for (int m = 0; m < 8; ++m) P[m]     = psig(Sp0[2*m], Sp0[2*m+1]);
            #pragma unroll
            for (int m = 0; m < 8; ++m) P[8 + m] = psig(Sp1[2*m], Sp1[2*m+1]);
            #pragma unroll
            for (int c2 = 0; c2 < 4; ++c2) {
                const uint32_t* Q = P + (c2 >> 1) * 8;
                const int t4 = (c2 & 1) * 4;
                R[2*c2]   = __shfl_xor(h ? Q[t4]     : Q[t4 + 2], 32);
                R[2*c2+1] = __shfl_xor(h ? Q[t4 + 1] : Q[t4 + 3], 32);
            }
        }

        if (t + 1 < NT) stage_tile(b ^ 1);   // regs hold tile t+1
        if (t + 2 < NT) load_tile(t + 2);    // refill consumed regs

        // ---- interleaved MFMA block: two independent streams ----
        floatx16 S0, S1;
        #pragma unroll
        for (int i = 0; i < 16; ++i) { S0[i] = 0.0f; S1[i] = 0.0f; }
        #pragma unroll
        for (int u = 0; u < 4; ++u) {
            if (t < NT) {
                S0 = __builtin_amdgcn_mfma_f32_32x32x16_f16(A10[u], Xf[u], S0, 0, 0, 0);
                S1 = __builtin_amdgcn_mfma_f32_32x32x16_f16(A11[u], Xf[u], S1, 0, 0, 0);
            }
            if (t > 0) {
                const uint32_t* Q = P + (u >> 1) * 8;
                const int t4 = (u & 1) * 4;
                half8 B = h ? mk_frag(R[2*u], R[2*u+1], Q[t4 + 2], Q[t4 + 3])
                            : mk_frag(Q[t4], Q[t4 + 1], R[2*u], R[2*u+1]);
                F0 = __builtin_amdgcn_mfma_f32_32x32x16_f16(A2p0[u], B, F0, 0, 0, 0);
                F1 = __builtin_amdgcn_mfma_f32_32x32x16_f16(A2p1[u], B, F1, 0, 0, 0);
            }
        }

        if (t < NT) {
            // GEMM2 A-frags for THIS tile, carried to t+1 (buf b valid until barrier)
            #pragma unroll
            for (int c2 = 0; c2 < 4; ++c2) {
                A2p0[c2] = *(const half8*)&Ut3[l31][16 * c2 + 8 * h];
                A2p1[c2] = *(const half8*)&Ut3[32 + l31][16 * c2 + 8 * h];
            }
            Sp0 = S0; Sp1 = S1;
            __syncthreads();
        }
    }

    // ---- epilogue: direct store ----
    float* op = out + (size_t)lw * ND + n * 64;
    #pragma unroll
    for (int q = 0; q < 4; ++q) {
        float4 a; a.x = F0[4*q]; a.y = F0[4*q+1]; a.z = F0[4*q+2]; a.w = F0[4*q+3];
        *(float4*)(op + 8*q + 4*h) = a;               // d 0..31
        float4 bq; bq.x = F1[4*q]; bq.y = F1[4*q+1]; bq.z = F1[4*q+2]; bq.w = F1[4*q+3];
        *(float4*)(op + 32 + 8*q + 4*h) = bq;         // d 32..63
    }
}

extern "C" void kernel_launch(void* const* d_in, const int* in_sizes, int n_in,
                              void* d_out, int out_size, void* d_ws, size_t ws_size,
                              hipStream_t stream)
{
    const float* x  = (const float*)d_in[0];
    const float* up = (const float*)d_in[1];
    float* out      = (float*)d_out;
    corr_kernel<<<dim3(64, 8), dim3(256), 0, stream>>>(x, up, out);
}